// Round 7
// baseline (525.591 us; speedup 1.0000x reference)
//
#include <hip/hip_runtime.h>

typedef _Float16 half_t;
typedef _Float16 f16x8 __attribute__((ext_vector_type(8)));
typedef float    f32x4 __attribute__((ext_vector_type(4)));

typedef __attribute__((address_space(1))) const void void_g;
typedef __attribute__((address_space(3))) void void_l;
#define GLOAD_LDS16(gp, lp) __builtin_amdgcn_global_load_lds((void_g*)(gp), (void_l*)(lp), 16, 0, 0)

constexpr int B_ = 4, S_ = 2048, DIN_ = 2048, H_ = 16, HD_ = 128, G_ = 4, DOUT_ = 2048;
constexpr int NC_ = 5120;  // 2048 q | 512 k | 512 v | 2048 gate

// ---------------- elementwise fp32 -> fp16 ----------------
__global__ __launch_bounds__(256) void cvt_f16(const float* __restrict__ in,
                                               half_t* __restrict__ out, int n4) {
  int i = blockIdx.x * blockDim.x + threadIdx.x;
  if (i < n4) {
    float4 v = reinterpret_cast<const float4*>(in)[i];
    union { half_t h[4]; uint2 u; } pk;
    pk.h[0] = (half_t)v.x; pk.h[1] = (half_t)v.y;
    pk.h[2] = (half_t)v.z; pk.h[3] = (half_t)v.w;
    reinterpret_cast<uint2*>(out)[i] = pk.u;
  }
}

// ---------------- fp32 (R x C) -> fp16 transposed (C x R) ----------------
__global__ __launch_bounds__(256) void transpose_cvt(const float* __restrict__ in,
                                                     half_t* __restrict__ out, int R, int C) {
  __shared__ float t[32][33];
  int tx = threadIdx.x, ty = threadIdx.y;
  int c0 = blockIdx.x * 32, r0 = blockIdx.y * 32;
#pragma unroll
  for (int i = ty; i < 32; i += 8) t[i][tx] = in[(size_t)(r0 + i) * C + c0 + tx];
  __syncthreads();
#pragma unroll
  for (int i = ty; i < 32; i += 8)
    out[(size_t)(c0 + i) * R + r0 + tx] = (half_t)t[tx][i];
}

// ---------------- 256x256 GEMM, 4 phases/K-tile, intra-tile phase-ahead reads.
// No read ever crosses the tile-certification barrier (fixes the R6 race).
__device__ __forceinline__ void storeC(half_t* p, float v) { *p = (half_t)v; }
__device__ __forceinline__ void storeC(float* p, float v)  { *p = v; }

#define BARRIER   asm volatile("s_barrier" ::: "memory")
#define LGKM(N)   asm volatile("s_waitcnt lgkmcnt(" #N ")" ::: "memory"); __builtin_amdgcn_sched_barrier(0)
#define VMCNT4    asm volatile("s_waitcnt vmcnt(4)" ::: "memory")

template <typename OutT>
__global__ __launch_bounds__(512, 2) void gemm256(const half_t* __restrict__ A,
                                                  const half_t* __restrict__ Bt,
                                                  OutT* __restrict__ C,
                                                  int M, int N, int K) {
  __shared__ alignas(16) half_t Ash[2][256 * 64];
  __shared__ alignas(16) half_t Bsh[2][256 * 64];
  const int lane = threadIdx.x & 63;
  const int wid  = threadIdx.x >> 6;
  const int lq = lane & 15, lg = lane >> 4;
  const int wm = wid >> 2, wn = wid & 3;

  // XCD-aware bijective swizzle (block count is a multiple of 8)
  const int gx = gridDim.x;
  int wgid = blockIdx.y * gx + blockIdx.x;
  const int chunk = (gx * gridDim.y) >> 3;
  wgid = (wgid & 7) * chunk + (wgid >> 3);
  const int mb = wgid / gx, nb = wgid - mb * gx;

  const half_t* Ab = A  + (size_t)(mb * 256) * K;
  const half_t* Bb = Bt + (size_t)(nb * 256) * K;
  const int nk = K >> 6;

  // LDS row maps (ldsrow -> global row): A swaps row bits 6,7; B swaps bit7<->bit5,
  // so each 128-row stage chunk is exactly a quadrant-consumption set.
  auto stageA = [&](int s, int kt, int bsel) {
#pragma unroll
    for (int j = 0; j < 2; ++j) {
      const int lr = s * 128 + j * 64 + wid * 8 + (lane >> 3);
      const int gr = (lr & 63) | ((lr & 64) << 1) | ((lr & 128) >> 1);
      const half_t* src = Ab + (size_t)gr * K + kt * 64 + (((lane & 7) ^ (lr & 7)) << 3);
      GLOAD_LDS16(src, &Ash[bsel][(s * 128 + j * 64 + wid * 8) * 64]);
    }
  };
  auto stageB = [&](int s, int kt, int bsel) {
#pragma unroll
    for (int j = 0; j < 2; ++j) {
      const int lr = s * 128 + j * 64 + wid * 8 + (lane >> 3);
      const int gr = (((lr & 127) >> 5) << 6) + (lr & 31) + ((lr >> 7) << 5);
      const half_t* src = Bb + (size_t)gr * K + kt * 64 + (((lane & 7) ^ (lr & 7)) << 3);
      GLOAD_LDS16(src, &Bsh[bsel][(s * 128 + j * 64 + wid * 8) * 64]);
    }
  };

  f16x8 aF[4], aG[4];  // A fragments (rotating)
  f16x8 bfx[4][2];     // all B fragments for the K-tile
  f32x4 acc[8][4];
#pragma unroll
  for (int i = 0; i < 8; ++i)
#pragma unroll
    for (int j = 0; j < 4; ++j) acc[i][j] = (f32x4){0.f, 0.f, 0.f, 0.f};

  auto readA = [&](f16x8* dst, const half_t* ab, int mh, int kk) {
#pragma unroll
    for (int mi = 0; mi < 4; ++mi) {
      const int lr = mh * 128 + wm * 64 + mi * 16 + lq;
      const int slot = ((kk << 2) + lg) ^ (lq & 7);
      dst[mi] = *reinterpret_cast<const f16x8*>(ab + lr * 64 + slot * 8);
    }
  };
  auto readB = [&](const half_t* bb, int kk) {
#pragma unroll
    for (int njj = 0; njj < 4; ++njj) {
      const int lr = (njj >> 1) * 128 + wn * 32 + (njj & 1) * 16 + lq;
      const int slot = ((kk << 2) + lg) ^ (lq & 7);
      bfx[njj][kk] = *reinterpret_cast<const f16x8*>(bb + lr * 64 + slot * 8);
    }
  };

#define MFMA_PH(MH, AR, KK)                                                    \
  __builtin_amdgcn_s_setprio(1);                                               \
  _Pragma("unroll")                                                             \
  for (int mi = 0; mi < 4; ++mi)                                                \
    _Pragma("unroll")                                                           \
    for (int njj = 0; njj < 4; ++njj)                                           \
      acc[(MH) * 4 + mi][njj] = __builtin_amdgcn_mfma_f32_16x16x32_f16(         \
          AR[mi], bfx[njj][KK], acc[(MH) * 4 + mi][njj], 0, 0, 0);              \
  __builtin_amdgcn_s_setprio(0);

  // Prologue: tile0 fully + tile1 s0-chunks; drain tile0 (certified at BARRIER),
  // keep tile1-s0's 4 loads in flight.
  stageA(0, 0, 0); stageA(1, 0, 0); stageB(0, 0, 0); stageB(1, 0, 0);
  stageA(0, 1, 1); stageB(0, 1, 1);
  VMCNT4;
  BARRIER;

#pragma unroll 1
  for (int T = 0; T < nk; ++T) {
    const int cur = T & 1, o = cur ^ 1;
    const int kt1 = (T + 1 < nk) ? T + 1 : nk - 1;  // tail: stage valid,
    const int kt2 = (T + 2 < nk) ? T + 2 : nk - 1;  // never-read data
    const half_t* ac = Ash[cur];
    const half_t* bc = Bsh[cur];
    // ---- P0: issue all mh0 reads (16); wait first 8; MFMA(mh0,kk0) ----
    readA(aF, ac, 0, 0); readB(bc, 0);
    readA(aG, ac, 0, 1); readB(bc, 1);
    LGKM(8);
    MFMA_PH(0, aF, 0);
    BARRIER;
    // ---- P1: stage s1(T+1)->o; read aF(mh1,kk0); wait P0 remainder; MFMA(mh0,kk1) ----
    stageA(1, kt1, o); stageB(1, kt1, o);
    readA(aF, ac, 1, 0);
    LGKM(4);
    MFMA_PH(0, aG, 1);
    BARRIER;
    // ---- P2: stage A-s0(T+2)->cur; read aG(mh1,kk1); MFMA(mh1,kk0) ----
    stageA(0, kt2, cur);
    readA(aG, ac, 1, 1);
    LGKM(4);
    MFMA_PH(1, aF, 0);
    BARRIER;
    // ---- P3: stage B-s0(T+2)->cur; MFMA(mh1,kk1); vmcnt(4) certifies tile T+1 ----
    stageB(0, kt2, cur);
    LGKM(0);
    MFMA_PH(1, aG, 1);
    VMCNT4;
    BARRIER;
  }

#pragma unroll
  for (int m8 = 0; m8 < 8; ++m8) {
#pragma unroll
    for (int r = 0; r < 4; ++r) {
      const size_t row = (size_t)(mb * 256 + wm * 128 + m8 * 16 + lg * 4 + r);
#pragma unroll
      for (int n4 = 0; n4 < 4; ++n4) {
        const int col = nb * 256 + wn * 64 + n4 * 16 + lq;
        storeC(&C[row * N + col], acc[m8][n4][r]);
      }
    }
  }
#undef MFMA_PH
}

// ---------------- RMSNorm + RoPE for Q and K (Q pre-scaled by log2e/sqrt(HD)) ----------------
__global__ __launch_bounds__(256) void post_qk(const half_t* __restrict__ QKVG,
                                               half_t* __restrict__ Q, half_t* __restrict__ Kd,
                                               const float* __restrict__ cosT,
                                               const float* __restrict__ sinT,
                                               const float* __restrict__ q_scale,
                                               const float* __restrict__ k_scale) {
  const int row  = blockIdx.x;                      // b*S + s
  const int slot = blockIdx.y * 4 + (threadIdx.x >> 6);  // 0..15 q heads, 16..19 k heads
  const int lane = threadIdx.x & 63;
  const int b = row >> 11, s = row & (S_ - 1);
  const bool isq = slot < 16;
  const int col0 = isq ? slot * 128 : 2048 + (slot - 16) * 128;
  float x0 = (float)QKVG[(size_t)row * NC_ + col0 + lane];
  float x1 = (float)QKVG[(size_t)row * NC_ + col0 + lane + 64];
  float ss = x0 * x0 + x1 * x1;
#pragma unroll
  for (int m = 1; m < 64; m <<= 1) ss += __shfl_xor(ss, m);
  float rms = rsqrtf(ss * (1.f / 128.f) + 1e-6f);
  const float* sc = isq ? q_scale : k_scale;
  float y0 = x0 * rms * (1.f + sc[lane]);
  float y1 = x1 * rms * (1.f + sc[lane + 64]);
  float c0 = cosT[s * 128 + lane], c1 = cosT[s * 128 + lane + 64];
  float s0 = sinT[s * 128 + lane], s1 = sinT[s * 128 + lane + 64];
  float r0 = y0 * c0 - y1 * s0;
  float r1 = y1 * c1 + y0 * s1;
  if (isq) { r0 *= 0.12751743f; r1 *= 0.12751743f; }  // (1/sqrt(128)) * log2(e)
  half_t* dst = isq ? (Q  + ((size_t)(b * H_ + slot) * S_ + s) * HD_)
                    : (Kd + ((size_t)(b * G_ + slot - 16) * S_ + s) * HD_);
  dst[lane]      = (half_t)r0;
  dst[lane + 64] = (half_t)r1;
}

// ---------------- V transpose: QKVG v-region -> VT (b,g,d,s) ----------------
__global__ __launch_bounds__(256) void v_transpose(const half_t* __restrict__ QKVG,
                                                   half_t* __restrict__ VT) {
  __shared__ half_t t[32][33];
  int tx = threadIdx.x, ty = threadIdx.y;
  int s0 = blockIdx.x * 32, d0 = blockIdx.y * 32;
  int bg = blockIdx.z;
  int b = bg >> 2, g = bg & 3;
#pragma unroll
  for (int i = ty; i < 32; i += 8)
    t[i][tx] = QKVG[(size_t)(b * S_ + s0 + i) * NC_ + 2560 + g * 128 + d0 + tx];
  __syncthreads();
#pragma unroll
  for (int i = ty; i < 32; i += 8)
    VT[((size_t)bg * 128 + d0 + i) * S_ + s0 + tx] = t[tx][i];
}

// ---------------- causal GQA flash attention + gate ----------------
__global__ __launch_bounds__(256) void flash_attn4(const half_t* __restrict__ Q,
                                                   const half_t* __restrict__ K,
                                                   const half_t* __restrict__ VT,
                                                   const half_t* __restrict__ QKVG,
                                                   half_t* __restrict__ ctxg) {
  __shared__ alignas(16) half_t Klds[3][32 * 128];
  __shared__ alignas(16) half_t Vlds[3][128 * 32];
  __shared__ alignas(16) half_t Plds[4][2][16 * 40];

  const int lane = threadIdx.x & 63;
  const int wid  = threadIdx.x >> 6;
  const int lq = lane & 15, lg = lane >> 4;
  const int qa = blockIdx.x;           // 0..7
  const int h = blockIdx.y, b = blockIdx.z;
  const int g = h >> 2;

  const half_t* Kb = K  + ((size_t)(b * G_ + g) * S_) * HD_;
  const half_t* Vb = VT + ((size_t)(b * G_ + g) * HD_) * S_;

  auto stage = [&](int kb, int bsel) {
#pragma unroll
    for (int ii = 0; ii < 2; ++ii) {
      const int i = wid * 2 + ii;
      {
        const int row  = i * 4 + lg;
        const int csrc = (lq * 16) ^ ((row & 7) << 4);
        GLOAD_LDS16(Kb + (size_t)(kb + row) * HD_ + (csrc >> 1), &Klds[bsel][i * 512]);
      }
      {
        const int d    = i * 16 + (lane >> 2);
        const int csrc = ((lane & 3) * 16) ^ (((d >> 1) & 3) << 4);
        GLOAD_LDS16(Vb + (size_t)d * S_ + kb + (csrc >> 1), &Vlds[bsel][i * 512]);
      }
    }
  };

#pragma unroll 1
  for (int seg = 0; seg < 2; ++seg) {
    const int qt = seg ? (15 - qa) : qa;
    const int q0w = qt * 128 + wid * 32;
    const half_t* Qb = Q + ((size_t)(b * H_ + h) * S_ + q0w) * HD_;

    f16x8 qf[2][4];
#pragma unroll
    for (int qs = 0; qs < 2; ++qs)
#pragma unroll
      for (int kc = 0; kc < 4; ++kc)
        qf[qs][kc] = *reinterpret_cast<const f16x8*>(Qb + (size_t)(qs * 16 + lq) * HD_ + kc * 32 + lg * 8);

    f32x4 O[2][8];
#pragma unroll
    for (int qs = 0; qs < 2; ++qs)
#pragma unroll
      for (int nc = 0; nc < 8; ++nc) O[qs][nc] = (f32x4){0.f, 0.f, 0.f, 0.f};
    float lf[2] = {0.f, 0.f};

    const int nt = 4 * qt + 4;
    const int qmax = q0w + 31;

    if (seg) {
      asm volatile("s_waitcnt vmcnt(0)" ::: "memory");
      __builtin_amdgcn_s_barrier();
    }
    stage(0, 0);
    stage(32, 1);
    asm volatile("s_waitcnt vmcnt(4)" ::: "memory");
    __builtin_amdgcn_s_barrier();

    int cur = 0;
#pragma unroll 1
    for (int t = 0; t < nt; ++t) {
      {
        const int t2 = (t + 2 < nt) ? t + 2 : nt - 1;
        int b2 = cur + 2; if (b2 >= 3) b2 -= 3;
        stage(t2 * 32, b2);
      }
      const int kb = t * 32;
      if (kb <= qmax) {
        const half_t* kbuf = Klds[cur];
        const half_t* vbuf = Vlds[cur];
        f32x4 sA[2][2];
#pragma unroll
        for (int qs = 0; qs < 2; ++qs)
#pragma unroll
          for (int ks = 0; ks < 2; ++ks) sA[qs][ks] = (f32x4){0.f, 0.f, 0.f, 0.f};
        __builtin_amdgcn_s_setprio(1);
#pragma unroll
        for (int kc = 0; kc < 4; ++kc)
#pragma unroll
          for (int ks = 0; ks < 2; ++ks) {
            const int row = ks * 16 + lq;
            const int off = row * 128 + ((((kc * 64 + lg * 16)) ^ ((row & 7) << 4)) >> 1);
            f16x8 kf = *reinterpret_cast<const f16x8*>(kbuf + off);
            sA[0][ks] = __builtin_amdgcn_mfma_f32_16x16x32_f16(kf, qf[0][kc], sA[0][ks], 0, 0, 0);
            sA[1][ks] = __builtin_amdgcn_mfma_f32_16x16x32_f16(kf, qf[1][kc], sA[1][ks], 0, 0, 0);
          }
        __builtin_amdgcn_s_setprio(0);
        f16x8 pf[2];
#pragma unroll
        for (int qs = 0; qs < 2; ++qs) {
          const int qg = q0w + qs * 16 + lq;
          const bool diag = (kb + 31 > q0w + qs * 16);
          float rs = 0.f;
          union { half_t hh[8]; uint2 u2[2]; } pk;
#pragma unroll
          for (int ks = 0; ks < 2; ++ks)
#pragma unroll
            for (int r = 0; r < 4; ++r) {
              float sv = sA[qs][ks][r];
              if (diag) {
                const int key = kb + ks * 16 + lg * 4 + r;
                if (key > qg) sv = -1e9f;
              }
              const float p = __builtin_amdgcn_exp2f(sv - 1.5f);
              rs += p;
              pk.hh[ks * 4 + r] = (half_t)p;
            }
          lf[qs] += rs;
          half_t* Pw = &Plds[wid][qs][0];
          *reinterpret_cast<uint2*>(Pw + lq * 40 + lg * 4)      = pk.u2[0];
          *reinterpret_cast<uint2*>(Pw + lq * 40 + 16 + lg * 4) = pk.u2[1];
        }
        pf[0] = *reinterpret_cast<const f16x8*>(&Plds[wid][0][0] + lq * 40 + lg * 8);
        pf[1] = *reinterpret_cast<const f16x8*>(&Plds[wid][1][0] + lq * 40 + lg * 8);
        __builtin_amdgcn_s_setprio(1);
#pragma unroll
        for (int nc = 0; nc < 8; ++nc) {
          const int d = nc * 16 + lq;
          const int off = d * 32 + (((lg * 16) ^ (((d >> 1) & 3) << 4)) >> 1);
          f16x8 vf = *reinterpret_cast<const f16x8*>(vbuf + off);
          O[0][nc] = __builtin_amdgcn_mfma_f32_16x16x32_f16(vf, pf[0], O[0][nc], 0, 0, 0);
          O[1][nc] = __builtin_amdgcn_mfma_f32_16x16x32_f16(vf, pf[1], O[1][nc], 0, 0, 0);
        }
        __builtin_amdgcn_s_setprio(0);
      }
      asm volatile("s_waitcnt vmcnt(4)" ::: "memory");
      __builtin_amdgcn_s_barrier();
      cur = (cur == 2) ? 0 : cur + 1;
    }

#pragma unroll
    for (int qs = 0; qs < 2; ++qs) {
      float l = lf[qs];
      l += __shfl_xor(l, 16);
      l += __shfl_xor(l, 32);
      const float linv = 1.f / l;
      const int qg = q0w + qs * 16 + lq;
      const size_t row = (size_t)b * S_ + qg;
#pragma unroll
      for (int nc = 0; nc < 8; ++nc) {
        const int col = h * 128 + nc * 16 + lg * 4;
        union { uint2 u; half_t hh[4]; } gg;
        gg.u = *reinterpret_cast<const uint2*>(QKVG + row * NC_ + 3072 + col);
        union { half_t hh[4]; uint2 u; } ov;
#pragma unroll
        for (int r = 0; r < 4; ++r) {
          const float gate = 1.f / (1.f + __expf(-(float)gg.hh[r]));
          ov.hh[r] = (half_t)(O[qs][nc][r] * linv * gate);
        }
        *reinterpret_cast<uint2*>(ctxg + row * DOUT_ + col) = ov.u;
      }
    }
  }
}

extern "C" void kernel_launch(void* const* d_in, const int* in_sizes, int n_in,
                              void* d_out, int out_size, void* d_ws, size_t ws_size,
                              hipStream_t stream) {
  const float* x     = (const float*)d_in[0];
  const float* cosT  = (const float*)d_in[3];
  const float* sinT  = (const float*)d_in[4];
  const float* Wq    = (const float*)d_in[5];
  const float* Wk    = (const float*)d_in[6];
  const float* Wv    = (const float*)d_in[7];
  const float* Wg    = (const float*)d_in[8];
  const float* Wo    = (const float*)d_in[9];
  const float* q_scale = (const float*)d_in[10];
  const float* k_scale = (const float*)d_in[11];
  float* out = (float*)d_out;

  const size_t MB = 1ull << 20;
  char* w = (char*)d_ws;
  half_t* xh   = (half_t*)(w);             // 32 MB
  half_t* ctxg = (half_t*)(w);             // reuse after GEMM1
  half_t* WT   = (half_t*)(w + 32 * MB);   // 20 MB
  half_t* WoT  = (half_t*)(w + 52 * MB);   // 8 MB
  half_t* QKVG = (half_t*)(w + 60 * MB);   // 80 MB
  half_t* Qh   = (half_t*)(w + 140 * MB);  // 32 MB
  half_t* Kh   = (half_t*)(w + 172 * MB);  // 8 MB
  half_t* VTh  = (half_t*)(w + 180 * MB);  // 8 MB

  dim3 tb(32, 8);
  cvt_f16<<<16384, 256, 0, stream>>>(x, xh, B_ * S_ * DIN_ / 4);
  transpose_cvt<<<dim3(64, 64), tb, 0, stream>>>(Wq, WT,                     2048, 2048);
  transpose_cvt<<<dim3(16, 64), tb, 0, stream>>>(Wk, WT + 2048 * 2048,       2048, 512);
  transpose_cvt<<<dim3(16, 64), tb, 0, stream>>>(Wv, WT + 2560 * 2048,       2048, 512);
  transpose_cvt<<<dim3(64, 64), tb, 0, stream>>>(Wg, WT + (size_t)3072 * 2048, 2048, 2048);
  transpose_cvt<<<dim3(64, 64), tb, 0, stream>>>(Wo, WoT,                    2048, 2048);

  gemm256<half_t><<<dim3(20, 32), 512, 0, stream>>>(xh, WT, QKVG, 8192, NC_, 2048);

  post_qk<<<dim3(8192, 5), 256, 0, stream>>>(QKVG, Qh, Kh, cosT, sinT, q_scale, k_scale);
  v_transpose<<<dim3(64, 4, 16), tb, 0, stream>>>(QKVG, VTh);

  flash_attn4<<<dim3(8, 16, 4), 256, 0, stream>>>(Qh, Kh, VTh, QKVG, ctxg);

  gemm256<float><<<dim3(8, 32), 512, 0, stream>>>(ctxg, WoT, out, 8192, 2048, 2048);
}

// Round 8
// 490.445 us; speedup vs baseline: 1.0717x; 1.0717x over previous
//
#include <hip/hip_runtime.h>

typedef _Float16 half_t;
typedef _Float16 f16x8 __attribute__((ext_vector_type(8)));
typedef float    f32x4 __attribute__((ext_vector_type(4)));

typedef __attribute__((address_space(1))) const void void_g;
typedef __attribute__((address_space(3))) void void_l;
#define GLOAD_LDS16(gp, lp) __builtin_amdgcn_global_load_lds((void_g*)(gp), (void_l*)(lp), 16, 0, 0)

constexpr int B_ = 4, S_ = 2048, DIN_ = 2048, H_ = 16, HD_ = 128, G_ = 4, DOUT_ = 2048;
constexpr int NC_ = 5120;  // 2048 q | 512 k | 512 v | 2048 gate

// ---------------- elementwise fp32 -> fp16 ----------------
__global__ __launch_bounds__(256) void cvt_f16(const float* __restrict__ in,
                                               half_t* __restrict__ out, int n4) {
  int i = blockIdx.x * blockDim.x + threadIdx.x;
  if (i < n4) {
    float4 v = reinterpret_cast<const float4*>(in)[i];
    union { half_t h[4]; uint2 u; } pk;
    pk.h[0] = (half_t)v.x; pk.h[1] = (half_t)v.y;
    pk.h[2] = (half_t)v.z; pk.h[3] = (half_t)v.w;
    reinterpret_cast<uint2*>(out)[i] = pk.u;
  }
}

// ---------------- fp32 (R x C) -> fp16 transposed (C x R) ----------------
__global__ __launch_bounds__(256) void transpose_cvt(const float* __restrict__ in,
                                                     half_t* __restrict__ out, int R, int C) {
  __shared__ float t[32][33];
  int tx = threadIdx.x, ty = threadIdx.y;
  int c0 = blockIdx.x * 32, r0 = blockIdx.y * 32;
#pragma unroll
  for (int i = ty; i < 32; i += 8) t[i][tx] = in[(size_t)(r0 + i) * C + c0 + tx];
  __syncthreads();
#pragma unroll
  for (int i = ty; i < 32; i += 8)
    out[(size_t)(c0 + i) * R + r0 + tx] = (half_t)t[tx][i];
}

// ---------------- 256x128 GEMM, BK=32, 8 waves, per-wave 64x64, 2 blocks/CU.
// Triple-buffered LDS, stage t+2 each step, counted vmcnt(3), one barrier/step.
// Cross-block overlap hides read latency / barrier joins (m97 mechanism).
__device__ __forceinline__ void storeC(half_t* p, float v) { *p = (half_t)v; }
__device__ __forceinline__ void storeC(float* p, float v)  { *p = v; }

#define BARRIER   asm volatile("s_barrier" ::: "memory")
#define LGKM0     asm volatile("s_waitcnt lgkmcnt(0)" ::: "memory"); __builtin_amdgcn_sched_barrier(0)
#define VMCNT3    asm volatile("s_waitcnt vmcnt(3)" ::: "memory")

template <typename OutT>
__global__ __launch_bounds__(512, 4) void gemm_bk32(const half_t* __restrict__ A,
                                                    const half_t* __restrict__ Bt,
                                                    OutT* __restrict__ C,
                                                    int M, int N, int K) {
  __shared__ alignas(16) half_t Ash[3][256 * 32];
  __shared__ alignas(16) half_t Bsh[3][128 * 32];
  const int tid  = threadIdx.x;
  const int lane = tid & 63;
  const int wid  = tid >> 6;
  const int lq = lane & 15, lg = lane >> 4;
  const int wm = wid >> 1, wn = wid & 1;

  // XCD-aware bijective swizzle (block count is a multiple of 8)
  const int gx = gridDim.x;
  int wgid = blockIdx.y * gx + blockIdx.x;
  const int chunk = (gx * gridDim.y) >> 3;
  wgid = (wgid & 7) * chunk + (wgid >> 3);
  const int mb = wgid / gx, nb = wgid - mb * gx;

  const int nk = K >> 5;

  // Staging: per step, wave wid issues 3 gloads (A rows wid*32..+31 in 2, B rows wid*16..+15).
  // LDS[row][slot] = global[row][slot ^ (row&3)] (slot = 16B unit); read undoes the XOR.
  const int arow0 = wid * 32 + (lane >> 2);
  const int arow1 = arow0 + 16;
  const int brow  = wid * 16 + (lane >> 2);
  const half_t* aSrc0 = A  + (size_t)(mb * 256 + arow0) * K + (((lane & 3) ^ (arow0 & 3)) << 3);
  const half_t* aSrc1 = A  + (size_t)(mb * 256 + arow1) * K + (((lane & 3) ^ (arow1 & 3)) << 3);
  const half_t* bSrc  = Bt + (size_t)(nb * 128 + brow)  * K + (((lane & 3) ^ (brow  & 3)) << 3);

  auto stage = [&](int kt, int bsel) {
    GLOAD_LDS16(aSrc0 + kt * 32, &Ash[bsel][wid * 1024]);
    GLOAD_LDS16(aSrc1 + kt * 32, &Ash[bsel][wid * 1024 + 512]);
    GLOAD_LDS16(bSrc  + kt * 32, &Bsh[bsel][wid * 512]);
  };

  f32x4 acc[4][4];
#pragma unroll
  for (int i = 0; i < 4; ++i)
#pragma unroll
    for (int j = 0; j < 4; ++j) acc[i][j] = (f32x4){0.f, 0.f, 0.f, 0.f};

  const int rdslot = (lg ^ (lq & 3)) * 8;

  stage(0, 0);
  stage(1, 1);
  VMCNT3;
  BARRIER;

  int cur = 0;
#pragma unroll 1
  for (int t = 0; t < nk; ++t) {
    {  // prefetch tile t+2 (clamped at tail so vmcnt stays uniform)
      const int kt2 = (t + 2 < nk) ? t + 2 : nk - 1;
      int b2 = cur + 2; if (b2 >= 3) b2 -= 3;
      stage(kt2, b2);
    }
    f16x8 a4[4], b4[4];
#pragma unroll
    for (int mi = 0; mi < 4; ++mi)
      a4[mi] = *reinterpret_cast<const f16x8*>(&Ash[cur][(wm * 64 + mi * 16 + lq) * 32 + rdslot]);
#pragma unroll
    for (int nj = 0; nj < 4; ++nj)
      b4[nj] = *reinterpret_cast<const f16x8*>(&Bsh[cur][(wn * 64 + nj * 16 + lq) * 32 + rdslot]);
    LGKM0;
    __builtin_amdgcn_s_setprio(1);
#pragma unroll
    for (int mi = 0; mi < 4; ++mi)
#pragma unroll
      for (int nj = 0; nj < 4; ++nj)
        acc[mi][nj] = __builtin_amdgcn_mfma_f32_16x16x32_f16(a4[mi], b4[nj], acc[mi][nj], 0, 0, 0);
    __builtin_amdgcn_s_setprio(0);
    VMCNT3;     // tile t+1 certified; t+2's 3 loads stay in flight
    BARRIER;
    cur = (cur == 2) ? 0 : cur + 1;
  }

#pragma unroll
  for (int mi = 0; mi < 4; ++mi) {
#pragma unroll
    for (int r = 0; r < 4; ++r) {
      const size_t row = (size_t)(mb * 256 + wm * 64 + mi * 16 + lg * 4 + r);
#pragma unroll
      for (int nj = 0; nj < 4; ++nj) {
        const int col = nb * 128 + wn * 64 + nj * 16 + lq;
        storeC(&C[row * N + col], acc[mi][nj][r]);
      }
    }
  }
}

// ---------------- RMSNorm + RoPE for Q and K (Q pre-scaled by log2e/sqrt(HD)) ----------------
__global__ __launch_bounds__(256) void post_qk(const half_t* __restrict__ QKVG,
                                               half_t* __restrict__ Q, half_t* __restrict__ Kd,
                                               const float* __restrict__ cosT,
                                               const float* __restrict__ sinT,
                                               const float* __restrict__ q_scale,
                                               const float* __restrict__ k_scale) {
  const int row  = blockIdx.x;                      // b*S + s
  const int slot = blockIdx.y * 4 + (threadIdx.x >> 6);  // 0..15 q heads, 16..19 k heads
  const int lane = threadIdx.x & 63;
  const int b = row >> 11, s = row & (S_ - 1);
  const bool isq = slot < 16;
  const int col0 = isq ? slot * 128 : 2048 + (slot - 16) * 128;
  float x0 = (float)QKVG[(size_t)row * NC_ + col0 + lane];
  float x1 = (float)QKVG[(size_t)row * NC_ + col0 + lane + 64];
  float ss = x0 * x0 + x1 * x1;
#pragma unroll
  for (int m = 1; m < 64; m <<= 1) ss += __shfl_xor(ss, m);
  float rms = rsqrtf(ss * (1.f / 128.f) + 1e-6f);
  const float* sc = isq ? q_scale : k_scale;
  float y0 = x0 * rms * (1.f + sc[lane]);
  float y1 = x1 * rms * (1.f + sc[lane + 64]);
  float c0 = cosT[s * 128 + lane], c1 = cosT[s * 128 + lane + 64];
  float s0 = sinT[s * 128 + lane], s1 = sinT[s * 128 + lane + 64];
  float r0 = y0 * c0 - y1 * s0;
  float r1 = y1 * c1 + y0 * s1;
  if (isq) { r0 *= 0.12751743f; r1 *= 0.12751743f; }  // (1/sqrt(128)) * log2(e)
  half_t* dst = isq ? (Q  + ((size_t)(b * H_ + slot) * S_ + s) * HD_)
                    : (Kd + ((size_t)(b * G_ + slot - 16) * S_ + s) * HD_);
  dst[lane]      = (half_t)r0;
  dst[lane + 64] = (half_t)r1;
}

// ---------------- V transpose: QKVG v-region -> VT (b,g,d,s) ----------------
__global__ __launch_bounds__(256) void v_transpose(const half_t* __restrict__ QKVG,
                                                   half_t* __restrict__ VT) {
  __shared__ half_t t[32][33];
  int tx = threadIdx.x, ty = threadIdx.y;
  int s0 = blockIdx.x * 32, d0 = blockIdx.y * 32;
  int bg = blockIdx.z;
  int b = bg >> 2, g = bg & 3;
#pragma unroll
  for (int i = ty; i < 32; i += 8)
    t[i][tx] = QKVG[(size_t)(b * S_ + s0 + i) * NC_ + 2560 + g * 128 + d0 + tx];
  __syncthreads();
#pragma unroll
  for (int i = ty; i < 32; i += 8)
    VT[((size_t)bg * 128 + d0 + i) * S_ + s0 + tx] = t[tx][i];
}

// ---------------- causal GQA flash attention + gate ----------------
__global__ __launch_bounds__(256) void flash_attn4(const half_t* __restrict__ Q,
                                                   const half_t* __restrict__ K,
                                                   const half_t* __restrict__ VT,
                                                   const half_t* __restrict__ QKVG,
                                                   half_t* __restrict__ ctxg) {
  __shared__ alignas(16) half_t Klds[3][32 * 128];
  __shared__ alignas(16) half_t Vlds[3][128 * 32];
  __shared__ alignas(16) half_t Plds[4][2][16 * 40];

  const int lane = threadIdx.x & 63;
  const int wid  = threadIdx.x >> 6;
  const int lq = lane & 15, lg = lane >> 4;
  const int qa = blockIdx.x;           // 0..7
  const int h = blockIdx.y, b = blockIdx.z;
  const int g = h >> 2;

  const half_t* Kb = K  + ((size_t)(b * G_ + g) * S_) * HD_;
  const half_t* Vb = VT + ((size_t)(b * G_ + g) * HD_) * S_;

  auto stage = [&](int kb, int bsel) {
#pragma unroll
    for (int ii = 0; ii < 2; ++ii) {
      const int i = wid * 2 + ii;
      {
        const int row  = i * 4 + lg;
        const int csrc = (lq * 16) ^ ((row & 7) << 4);
        GLOAD_LDS16(Kb + (size_t)(kb + row) * HD_ + (csrc >> 1), &Klds[bsel][i * 512]);
      }
      {
        const int d    = i * 16 + (lane >> 2);
        const int csrc = ((lane & 3) * 16) ^ (((d >> 1) & 3) << 4);
        GLOAD_LDS16(Vb + (size_t)d * S_ + kb + (csrc >> 1), &Vlds[bsel][i * 512]);
      }
    }
  };

#pragma unroll 1
  for (int seg = 0; seg < 2; ++seg) {
    const int qt = seg ? (15 - qa) : qa;
    const int q0w = qt * 128 + wid * 32;
    const half_t* Qb = Q + ((size_t)(b * H_ + h) * S_ + q0w) * HD_;

    f16x8 qf[2][4];
#pragma unroll
    for (int qs = 0; qs < 2; ++qs)
#pragma unroll
      for (int kc = 0; kc < 4; ++kc)
        qf[qs][kc] = *reinterpret_cast<const f16x8*>(Qb + (size_t)(qs * 16 + lq) * HD_ + kc * 32 + lg * 8);

    f32x4 O[2][8];
#pragma unroll
    for (int qs = 0; qs < 2; ++qs)
#pragma unroll
      for (int nc = 0; nc < 8; ++nc) O[qs][nc] = (f32x4){0.f, 0.f, 0.f, 0.f};
    float lf[2] = {0.f, 0.f};

    const int nt = 4 * qt + 4;
    const int qmax = q0w + 31;

    if (seg) {
      asm volatile("s_waitcnt vmcnt(0)" ::: "memory");
      __builtin_amdgcn_s_barrier();
    }
    stage(0, 0);
    stage(32, 1);
    asm volatile("s_waitcnt vmcnt(4)" ::: "memory");
    __builtin_amdgcn_s_barrier();

    int cur = 0;
#pragma unroll 1
    for (int t = 0; t < nt; ++t) {
      {
        const int t2 = (t + 2 < nt) ? t + 2 : nt - 1;
        int b2 = cur + 2; if (b2 >= 3) b2 -= 3;
        stage(t2 * 32, b2);
      }
      const int kb = t * 32;
      if (kb <= qmax) {
        const half_t* kbuf = Klds[cur];
        const half_t* vbuf = Vlds[cur];
        f32x4 sA[2][2];
#pragma unroll
        for (int qs = 0; qs < 2; ++qs)
#pragma unroll
          for (int ks = 0; ks < 2; ++ks) sA[qs][ks] = (f32x4){0.f, 0.f, 0.f, 0.f};
        __builtin_amdgcn_s_setprio(1);
#pragma unroll
        for (int kc = 0; kc < 4; ++kc)
#pragma unroll
          for (int ks = 0; ks < 2; ++ks) {
            const int row = ks * 16 + lq;
            const int off = row * 128 + ((((kc * 64 + lg * 16)) ^ ((row & 7) << 4)) >> 1);
            f16x8 kf = *reinterpret_cast<const f16x8*>(kbuf + off);
            sA[0][ks] = __builtin_amdgcn_mfma_f32_16x16x32_f16(kf, qf[0][kc], sA[0][ks], 0, 0, 0);
            sA[1][ks] = __builtin_amdgcn_mfma_f32_16x16x32_f16(kf, qf[1][kc], sA[1][ks], 0, 0, 0);
          }
        __builtin_amdgcn_s_setprio(0);
        f16x8 pf[2];
#pragma unroll
        for (int qs = 0; qs < 2; ++qs) {
          const int qg = q0w + qs * 16 + lq;
          const bool diag = (kb + 31 > q0w + qs * 16);
          float rs = 0.f;
          union { half_t hh[8]; uint2 u2[2]; } pk;
#pragma unroll
          for (int ks = 0; ks < 2; ++ks)
#pragma unroll
            for (int r = 0; r < 4; ++r) {
              float sv = sA[qs][ks][r];
              if (diag) {
                const int key = kb + ks * 16 + lg * 4 + r;
                if (key > qg) sv = -1e9f;
              }
              const float p = __builtin_amdgcn_exp2f(sv - 1.5f);
              rs += p;
              pk.hh[ks * 4 + r] = (half_t)p;
            }
          lf[qs] += rs;
          half_t* Pw = &Plds[wid][qs][0];
          *reinterpret_cast<uint2*>(Pw + lq * 40 + lg * 4)      = pk.u2[0];
          *reinterpret_cast<uint2*>(Pw + lq * 40 + 16 + lg * 4) = pk.u2[1];
        }
        pf[0] = *reinterpret_cast<const f16x8*>(&Plds[wid][0][0] + lq * 40 + lg * 8);
        pf[1] = *reinterpret_cast<const f16x8*>(&Plds[wid][1][0] + lq * 40 + lg * 8);
        __builtin_amdgcn_s_setprio(1);
#pragma unroll
        for (int nc = 0; nc < 8; ++nc) {
          const int d = nc * 16 + lq;
          const int off = d * 32 + (((lg * 16) ^ (((d >> 1) & 3) << 4)) >> 1);
          f16x8 vf = *reinterpret_cast<const f16x8*>(vbuf + off);
          O[0][nc] = __builtin_amdgcn_mfma_f32_16x16x32_f16(vf, pf[0], O[0][nc], 0, 0, 0);
          O[1][nc] = __builtin_amdgcn_mfma_f32_16x16x32_f16(vf, pf[1], O[1][nc], 0, 0, 0);
        }
        __builtin_amdgcn_s_setprio(0);
      }
      asm volatile("s_waitcnt vmcnt(4)" ::: "memory");
      __builtin_amdgcn_s_barrier();
      cur = (cur == 2) ? 0 : cur + 1;
    }

#pragma unroll
    for (int qs = 0; qs < 2; ++qs) {
      float l = lf[qs];
      l += __shfl_xor(l, 16);
      l += __shfl_xor(l, 32);
      const float linv = 1.f / l;
      const int qg = q0w + qs * 16 + lq;
      const size_t row = (size_t)b * S_ + qg;
#pragma unroll
      for (int nc = 0; nc < 8; ++nc) {
        const int col = h * 128 + nc * 16 + lg * 4;
        union { uint2 u; half_t hh[4]; } gg;
        gg.u = *reinterpret_cast<const uint2*>(QKVG + row * NC_ + 3072 + col);
        union { half_t hh[4]; uint2 u; } ov;
#pragma unroll
        for (int r = 0; r < 4; ++r) {
          const float gate = 1.f / (1.f + __expf(-(float)gg.hh[r]));
          ov.hh[r] = (half_t)(O[qs][nc][r] * linv * gate);
        }
        *reinterpret_cast<uint2*>(ctxg + row * DOUT_ + col) = ov.u;
      }
    }
  }
}

extern "C" void kernel_launch(void* const* d_in, const int* in_sizes, int n_in,
                              void* d_out, int out_size, void* d_ws, size_t ws_size,
                              hipStream_t stream) {
  const float* x     = (const float*)d_in[0];
  const float* cosT  = (const float*)d_in[3];
  const float* sinT  = (const float*)d_in[4];
  const float* Wq    = (const float*)d_in[5];
  const float* Wk    = (const float*)d_in[6];
  const float* Wv    = (const float*)d_in[7];
  const float* Wg    = (const float*)d_in[8];
  const float* Wo    = (const float*)d_in[9];
  const float* q_scale = (const float*)d_in[10];
  const float* k_scale = (const float*)d_in[11];
  float* out = (float*)d_out;

  const size_t MB = 1ull << 20;
  char* w = (char*)d_ws;
  half_t* xh   = (half_t*)(w);             // 32 MB
  half_t* ctxg = (half_t*)(w);             // reuse after GEMM1
  half_t* WT   = (half_t*)(w + 32 * MB);   // 20 MB
  half_t* WoT  = (half_t*)(w + 52 * MB);   // 8 MB
  half_t* QKVG = (half_t*)(w + 60 * MB);   // 80 MB
  half_t* Qh   = (half_t*)(w + 140 * MB);  // 32 MB
  half_t* Kh   = (half_t*)(w + 172 * MB);  // 8 MB
  half_t* VTh  = (half_t*)(w + 180 * MB);  // 8 MB

  dim3 tb(32, 8);
  cvt_f16<<<16384, 256, 0, stream>>>(x, xh, B_ * S_ * DIN_ / 4);
  transpose_cvt<<<dim3(64, 64), tb, 0, stream>>>(Wq, WT,                     2048, 2048);
  transpose_cvt<<<dim3(16, 64), tb, 0, stream>>>(Wk, WT + 2048 * 2048,       2048, 512);
  transpose_cvt<<<dim3(16, 64), tb, 0, stream>>>(Wv, WT + 2560 * 2048,       2048, 512);
  transpose_cvt<<<dim3(64, 64), tb, 0, stream>>>(Wg, WT + (size_t)3072 * 2048, 2048, 2048);
  transpose_cvt<<<dim3(64, 64), tb, 0, stream>>>(Wo, WoT,                    2048, 2048);

  gemm_bk32<half_t><<<dim3(40, 32), 512, 0, stream>>>(xh, WT, QKVG, 8192, NC_, 2048);

  post_qk<<<dim3(8192, 5), 256, 0, stream>>>(QKVG, Qh, Kh, cosT, sinT, q_scale, k_scale);
  v_transpose<<<dim3(64, 4, 16), tb, 0, stream>>>(QKVG, VTh);

  flash_attn4<<<dim3(8, 16, 4), 256, 0, stream>>>(Qh, Kh, VTh, QKVG, ctxg);

  gemm_bk32<float><<<dim3(16, 32), 512, 0, stream>>>(ctxg, WoT, out, 8192, 2048, 2048);
}